// Round 1
// baseline (434.430 us; speedup 1.0000x reference)
//
#include <hip/hip_runtime.h>

// CrossBlock: two-stream cross-attention + gated FFN, MI355X (gfx950).
// All heavy math in bf16 MFMA (16x16x32), f32 accumulate. attn01/attn10 are
// written exactly once (flash-style recompute for softmax stats), never re-read.

typedef unsigned short u16;
typedef unsigned int u32;
typedef __bf16 bf16x8 __attribute__((ext_vector_type(8)));
typedef float f32x4 __attribute__((ext_vector_type(4)));

#define DEV static __device__ __forceinline__

constexpr float MULT_ = 0.35355339059327373f;   // 64^-0.25
constexpr float L2E_  = 1.4426950408889634f;    // log2(e)

DEV u16 f2bf(float f){
  u32 u = __builtin_bit_cast(u32, f);
  return (u16)((u + 0x7FFFu + ((u >> 16) & 1u)) >> 16);  // RNE
}
DEV float bf2f(u16 h){ return __builtin_bit_cast(float, (u32)h << 16); }

DEV f32x4 mfma16(bf16x8 a, bf16x8 b, f32x4 c){
  return __builtin_amdgcn_mfma_f32_16x16x32_bf16(a, b, c, 0, 0, 0);
}

// ---------------- casts ----------------
__global__ __launch_bounds__(256) void cast_x_k(
    const float* __restrict__ x0, const float* __restrict__ x1,
    u16* __restrict__ xc0, u16* __restrict__ xc1)
{
  const float* x = blockIdx.y ? x1 : x0;
  u16* xc = blockIdx.y ? xc1 : xc0;
  int gs = gridDim.x * blockDim.x;
  for (int v = blockIdx.x*blockDim.x + threadIdx.x; v < 8192*64; v += gs){
    float4 f = ((const float4*)x)[v];
    int m = v >> 6, e4 = (v & 63) << 2;
    ushort4 o;
    o.x = f2bf(f.x); o.y = f2bf(f.y); o.z = f2bf(f.z); o.w = f2bf(f.w);
    *(ushort4*)&xc[(size_t)m*512 + e4] = o;   // xcat cols 0..255 = x
  }
}

__global__ __launch_bounds__(256) void cast_w_k(
    const float* __restrict__ Wqk, const float* __restrict__ Wv,
    const float* __restrict__ Wo,  const float* __restrict__ W1,
    const float* __restrict__ W2,
    u16* __restrict__ Wqkv, u16* __restrict__ WoB,
    u16* __restrict__ W1B,  u16* __restrict__ W2B)
{
  int gs = gridDim.x * blockDim.x;
  int t0 = blockIdx.x*blockDim.x + threadIdx.x;
  for (int t = t0; t < 512*256; t += gs)
    Wqkv[t] = f2bf(t < 65536 ? Wqk[t] : Wv[t - 65536]);
  for (int t = t0; t < 256*256; t += gs) WoB[t] = f2bf(Wo[t]);
  for (int t = t0; t < 512*512; t += gs) W1B[t] = f2bf(W1[t]);
  for (int t = t0; t < 256*512; t += gs) W2B[t] = f2bf(W2[t]);
}

// ---------------- generic 128x128 MFMA GEMM: C = A[M,K] * Bw[N,K]^T ----------------
// EPI 0: QKV  (bias bqk/bv; qk scaled by MULT_; writes qk[bh][n][d], v[bh][n][d])
// EPI 1: Wo   (bias bo; writes xcat[:,256+col])
// EPI 2: FFN1 (bias b1; writes h[m][col])
// EPI 3: FFN2 (bias b2 + residual x (f32); writes y to d_out)
template<int EPI, int K, int LDA, int NB>
__global__ __launch_bounds__(256) void gemm_k(
    const u16* __restrict__ A0, const u16* __restrict__ A1,
    const u16* __restrict__ Bw,
    const float* __restrict__ bias, const float* __restrict__ bias2,
    u16* __restrict__ O0, u16* __restrict__ O1,
    u16* __restrict__ P0, u16* __restrict__ P1,
    const float* __restrict__ R0, const float* __restrict__ R1,
    float* __restrict__ Y)
{
  constexpr int LSA = 40;                       // 32 + 8 pad -> 2-way (free) LDS reads
  __shared__ u16 As[128*LSA], Bs[128*LSA];
  const int tid = threadIdx.x, w = tid>>6, l = tid&63;
  const int s = blockIdx.z;
  const u16* A = s ? A1 : A0;
  const int m0 = blockIdx.x*128, n0 = blockIdx.y*128;
  const int wr = (w>>1)*64, wc = (w&1)*64;
  const f32x4 z4 = {0.f,0.f,0.f,0.f};
  f32x4 acc[4][4];
  #pragma unroll
  for (int i=0;i<4;++i)
    #pragma unroll
    for (int j=0;j<4;++j) acc[i][j] = z4;
  const int srow = tid>>2, scol = (tid&3)*8;
  for (int kt = 0; kt < K; kt += 32){
    __syncthreads();
    #pragma unroll
    for (int r = 0; r < 2; ++r){
      int row = r*64 + srow;
      *(uint4*)&As[row*LSA + scol] = *(const uint4*)&A[(size_t)(m0+row)*LDA + kt + scol];
      *(uint4*)&Bs[row*LSA + scol] = *(const uint4*)&Bw[(size_t)(n0+row)*K + kt + scol];
    }
    __syncthreads();
    bf16x8 af[4], bfr[4];
    #pragma unroll
    for (int mf=0; mf<4; ++mf)
      af[mf] = *(const bf16x8*)&As[(wr+mf*16+(l&15))*LSA + (l>>4)*8];
    #pragma unroll
    for (int nf=0; nf<4; ++nf)
      bfr[nf] = *(const bf16x8*)&Bs[(wc+nf*16+(l&15))*LSA + (l>>4)*8];
    #pragma unroll
    for (int mf=0; mf<4; ++mf)
      #pragma unroll
      for (int nf=0; nf<4; ++nf)
        acc[mf][nf] = mfma16(af[mf], bfr[nf], acc[mf][nf]);
  }
  u16* Oq = s ? O1 : O0;
  u16* Ov = s ? P1 : P0;
  const float* R = s ? R1 : R0;
  #pragma unroll
  for (int mf=0; mf<4; ++mf){
    #pragma unroll
    for (int nf=0; nf<4; ++nf){
      #pragma unroll
      for (int r=0; r<4; ++r){
        int row = m0 + wr + mf*16 + (l>>4)*4 + r;   // M index (C/D layout, m89-verified)
        int col = n0 + wc + nf*16 + (l&15);         // N index
        float v = acc[mf][nf][r];
        if constexpr (EPI==0){
          int bb = row >> 11, n = row & 2047;
          if (col < 256){
            float q = (v + bias[col]) * MULT_;
            int hh = col >> 6, d = col & 63;
            Oq[(size_t)((bb*4+hh)*2048 + n)*64 + d] = f2bf(q);
          } else {
            int c2 = col - 256;
            int hh = c2 >> 6, d = c2 & 63;
            Ov[(size_t)((bb*4+hh)*2048 + n)*64 + d] = f2bf(v + bias2[c2]);
          }
        } else if constexpr (EPI==1){
          Oq[(size_t)row*512 + 256 + col] = f2bf(v + bias[col]);
        } else if constexpr (EPI==2){
          Oq[(size_t)row*512 + col] = f2bf(v + bias[col]);
        } else {
          float* Yp = Y + (size_t)s*2097152;
          Yp[(size_t)row*256 + col] = v + bias[col] + R[(size_t)row*256 + col];
        }
      }
    }
  }
}

// ---------------- v[bh][n][d] -> vT[bh][d][n] ----------------
__global__ __launch_bounds__(256) void transp_k(
    const u16* __restrict__ v0, const u16* __restrict__ v1,
    u16* __restrict__ t0p, u16* __restrict__ t1p)
{
  __shared__ u16 t[64*66];
  const u16* vin = blockIdx.z ? v1 : v0;
  u16* vout = blockIdx.z ? t1p : t0p;
  int bh = blockIdx.y, j0 = blockIdx.x*64, tid = threadIdx.x;
  #pragma unroll
  for (int r=0;r<2;++r){
    int j = r*32 + (tid>>3), d = (tid&7)*8;
    *(uint4*)&t[j*66 + d] = *(const uint4*)&vin[((size_t)bh*2048 + j0 + j)*64 + d];
  }
  __syncthreads();
  #pragma unroll
  for (int r=0;r<2;++r){
    int d = r*32 + (tid>>3), j8 = (tid&7)*8;
    u32 p[4];
    #pragma unroll
    for (int k=0;k<4;++k){
      u32 lo = t[(j8+2*k)*66 + d];
      u32 hi = t[(j8+2*k+1)*66 + d];
      p[k] = lo | (hi<<16);
    }
    uint4 o = {p[0],p[1],p[2],p[3]};
    *(uint4*)&vout[((size_t)bh*64 + d)*2048 + j0 + j8] = o;
  }
}

// ---------------- softmax stats (online max/sumexp per row of sim (z=0) / sim^T (z=1)) ----------------
__global__ __launch_bounds__(256) void stats_k(
    const u16* __restrict__ qk0, const u16* __restrict__ qk1,
    float* __restrict__ rm0, float* __restrict__ rs0,
    float* __restrict__ rm1, float* __restrict__ rs1)
{
  __shared__ u16 Ks[128*72];
  const int z = blockIdx.z;
  const u16* Q  = z ? qk1 : qk0;
  const u16* Kp = z ? qk0 : qk1;
  float* rm = z ? rm1 : rm0;
  float* rs = z ? rs1 : rs0;
  const int bh = blockIdx.y, i0 = blockIdx.x*128;
  const int tid = threadIdx.x, w = tid>>6, l = tid&63;
  const u16* Qb = Q + (size_t)bh*2048*64;
  const u16* Kb = Kp + (size_t)bh*2048*64;
  bf16x8 qf[2][2];
  #pragma unroll
  for (int mf=0; mf<2; ++mf)
    #pragma unroll
    for (int kf=0; kf<2; ++kf)
      qf[mf][kf] = *(const bf16x8*)&Qb[(size_t)(i0 + w*32 + mf*16 + (l&15))*64 + kf*32 + (l>>4)*8];
  float rmv[2][4], rlv[2][4];
  #pragma unroll
  for (int mf=0;mf<2;++mf)
    #pragma unroll
    for (int r=0;r<4;++r){ rmv[mf][r] = -3.0e38f; rlv[mf][r] = 0.f; }
  const f32x4 z4 = {0.f,0.f,0.f,0.f};
  for (int jt=0; jt<2048; jt+=128){
    __syncthreads();
    #pragma unroll
    for (int r=0;r<4;++r){
      int row = r*32 + (tid>>3), c = (tid&7)*8;
      *(uint4*)&Ks[row*72 + c] = *(const uint4*)&Kb[(size_t)(jt+row)*64 + c];
    }
    __syncthreads();
    f32x4 acc[2][8];
    #pragma unroll
    for (int mf=0;mf<2;++mf)
      #pragma unroll
      for (int nf=0;nf<8;++nf) acc[mf][nf] = z4;
    #pragma unroll
    for (int nf=0; nf<8; ++nf){
      bf16x8 b0 = *(const bf16x8*)&Ks[(nf*16+(l&15))*72 + (l>>4)*8];
      bf16x8 b1 = *(const bf16x8*)&Ks[(nf*16+(l&15))*72 + 32 + (l>>4)*8];
      acc[0][nf] = mfma16(qf[0][0], b0, acc[0][nf]);
      acc[0][nf] = mfma16(qf[0][1], b1, acc[0][nf]);
      acc[1][nf] = mfma16(qf[1][0], b0, acc[1][nf]);
      acc[1][nf] = mfma16(qf[1][1], b1, acc[1][nf]);
    }
    #pragma unroll
    for (int mf=0; mf<2; ++mf)
      #pragma unroll
      for (int r=0; r<4; ++r){
        float tm = acc[mf][0][r];
        #pragma unroll
        for (int nf=1; nf<8; ++nf) tm = fmaxf(tm, acc[mf][nf][r]);
        tm = fmaxf(tm, __shfl_xor(tm, 1));
        tm = fmaxf(tm, __shfl_xor(tm, 2));
        tm = fmaxf(tm, __shfl_xor(tm, 4));
        tm = fmaxf(tm, __shfl_xor(tm, 8));
        float nm = fmaxf(rmv[mf][r], tm);
        float ps = 0.f;
        #pragma unroll
        for (int nf=0; nf<8; ++nf) ps += exp2f((acc[mf][nf][r]-nm)*L2E_);
        ps += __shfl_xor(ps, 1);
        ps += __shfl_xor(ps, 2);
        ps += __shfl_xor(ps, 4);
        ps += __shfl_xor(ps, 8);
        rlv[mf][r] = rlv[mf][r]*exp2f((rmv[mf][r]-nm)*L2E_) + ps;
        rmv[mf][r] = nm;
      }
  }
  if ((l&15)==0){
    #pragma unroll
    for (int mf=0;mf<2;++mf)
      #pragma unroll
      for (int r=0;r<4;++r){
        int i = i0 + w*32 + mf*16 + (l>>4)*4 + r;
        rm[bh*2048 + i] = rmv[mf][r];
        rs[bh*2048 + i] = rlv[mf][r];
      }
  }
}

// ---------------- fused: recompute sim tile, write attn rows, accumulate P*V ----------------
__global__ __launch_bounds__(256) void attn_k(
    const u16* __restrict__ qk0, const u16* __restrict__ qk1,
    const u16* __restrict__ vT0, const u16* __restrict__ vT1,
    const float* __restrict__ rm0, const float* __restrict__ rs0,
    const float* __restrict__ rm1, const float* __restrict__ rs1,
    u16* __restrict__ mo0, u16* __restrict__ mo1,
    float* __restrict__ dout)
{
  __shared__ u16 Ks[128*72];
  __shared__ u16 Vs[64*136];
  __shared__ u16 Ps[128*136];
  const int z = blockIdx.z;
  const u16* Q  = z ? qk1 : qk0;
  const u16* Kp = z ? qk0 : qk1;
  const u16* Vp = z ? vT0 : vT1;
  const float* rm = z ? rm1 : rm0;
  const float* rs = z ? rs1 : rs0;
  u16* mo = z ? mo1 : mo0;
  const int bh = blockIdx.y, i0 = blockIdx.x*128;
  float* aout = dout + (size_t)(z ? 71303168u : 4194304u) + (size_t)bh*4194304u;
  const int tid = threadIdx.x, w = tid>>6, l = tid&63;
  const u16* Qb = Q + (size_t)bh*2048*64;
  const u16* Kb = Kp + (size_t)bh*2048*64;
  const u16* Vb = Vp + (size_t)bh*64*2048;
  bf16x8 qf[2][2];
  #pragma unroll
  for (int mf=0; mf<2; ++mf)
    #pragma unroll
    for (int kf=0; kf<2; ++kf)
      qf[mf][kf] = *(const bf16x8*)&Qb[(size_t)(i0 + w*32 + mf*16 + (l&15))*64 + kf*32 + (l>>4)*8];
  float rmr[2][4], rir[2][4];
  #pragma unroll
  for (int mf=0;mf<2;++mf)
    #pragma unroll
    for (int r=0;r<4;++r){
      int i = i0 + w*32 + mf*16 + (l>>4)*4 + r;
      rmr[mf][r] = rm[bh*2048 + i];
      rir[mf][r] = 1.f / rs[bh*2048 + i];
    }
  const f32x4 z4 = {0.f,0.f,0.f,0.f};
  f32x4 macc[2][4];
  #pragma unroll
  for (int mf=0;mf<2;++mf)
    #pragma unroll
    for (int nf=0;nf<4;++nf) macc[mf][nf] = z4;
  for (int jt=0; jt<2048; jt+=128){
    __syncthreads();
    #pragma unroll
    for (int r=0;r<4;++r){
      int row = r*32 + (tid>>3), c = (tid&7)*8;
      *(uint4*)&Ks[row*72 + c] = *(const uint4*)&Kb[(size_t)(jt+row)*64 + c];
    }
    #pragma unroll
    for (int r=0;r<4;++r){
      int d = r*16 + (tid>>4), c = (tid&15)*8;
      *(uint4*)&Vs[d*136 + c] = *(const uint4*)&Vb[(size_t)d*2048 + jt + c];
    }
    __syncthreads();
    f32x4 acc[2][8];
    #pragma unroll
    for (int mf=0;mf<2;++mf)
      #pragma unroll
      for (int nf=0;nf<8;++nf) acc[mf][nf] = z4;
    #pragma unroll
    for (int nf=0; nf<8; ++nf){
      bf16x8 b0 = *(const bf16x8*)&Ks[(nf*16+(l&15))*72 + (l>>4)*8];
      bf16x8 b1 = *(const bf16x8*)&Ks[(nf*16+(l&15))*72 + 32 + (l>>4)*8];
      acc[0][nf] = mfma16(qf[0][0], b0, acc[0][nf]);
      acc[0][nf] = mfma16(qf[0][1], b1, acc[0][nf]);
      acc[1][nf] = mfma16(qf[1][0], b0, acc[1][nf]);
      acc[1][nf] = mfma16(qf[1][1], b1, acc[1][nf]);
    }
    #pragma unroll
    for (int mf=0;mf<2;++mf)
      #pragma unroll
      for (int nf=0;nf<8;++nf){
        int coll = nf*16 + (l&15);
        #pragma unroll
        for (int r=0;r<4;++r){
          int rowl = w*32 + mf*16 + (l>>4)*4 + r;
          float p = exp2f((acc[mf][nf][r]-rmr[mf][r])*L2E_) * rir[mf][r];
          aout[(size_t)(i0+rowl)*2048 + jt + coll] = p;
          Ps[rowl*136 + coll] = f2bf(p);
        }
      }
    __syncthreads();
    #pragma unroll
    for (int kf=0; kf<4; ++kf){
      bf16x8 pa0 = *(const bf16x8*)&Ps[(w*32 + (l&15))*136 + kf*32 + (l>>4)*8];
      bf16x8 pa1 = *(const bf16x8*)&Ps[(w*32 + 16 + (l&15))*136 + kf*32 + (l>>4)*8];
      #pragma unroll
      for (int nf=0; nf<4; ++nf){
        bf16x8 vb = *(const bf16x8*)&Vs[(nf*16+(l&15))*136 + kf*32 + (l>>4)*8];
        macc[0][nf] = mfma16(pa0, vb, macc[0][nf]);
        macc[1][nf] = mfma16(pa1, vb, macc[1][nf]);
      }
    }
  }
  int bb = bh>>2, hh = bh&3;
  #pragma unroll
  for (int mf=0;mf<2;++mf)
    #pragma unroll
    for (int nf=0;nf<4;++nf)
      #pragma unroll
      for (int r=0;r<4;++r){
        int n = i0 + w*32 + mf*16 + (l>>4)*4 + r;
        int d = nf*16 + (l&15);
        mo[(size_t)(bb*2048 + n)*256 + hh*64 + d] = f2bf(macc[mf][nf][r]);
      }
}

// ---------------- LayerNorm + exact GELU, in place on h[8192][512] ----------------
__global__ __launch_bounds__(256) void ln_gelu_k(
    u16* __restrict__ h0, u16* __restrict__ h1,
    const float* __restrict__ g, const float* __restrict__ be)
{
  u16* h = blockIdx.y ? h1 : h0;
  int row = blockIdx.x*4 + (threadIdx.x>>6);
  int l = threadIdx.x & 63;
  u16* hr = h + (size_t)row*512;
  uint4 raw = *(const uint4*)&hr[l*8];
  u32 ua[4] = {raw.x, raw.y, raw.z, raw.w};
  float f[8];
  #pragma unroll
  for (int k=0;k<4;++k){
    f[2*k]   = bf2f((u16)(ua[k] & 0xFFFFu));
    f[2*k+1] = bf2f((u16)(ua[k] >> 16));
  }
  float s = 0.f, s2 = 0.f;
  #pragma unroll
  for (int k=0;k<8;++k){ s += f[k]; s2 += f[k]*f[k]; }
  #pragma unroll
  for (int o=1;o<64;o<<=1){ s += __shfl_xor(s,o); s2 += __shfl_xor(s2,o); }
  float mean = s * (1.f/512.f);
  float var  = s2 * (1.f/512.f) - mean*mean;
  float rstd = rsqrtf(var + 1e-5f);
  u32 ob[4];
  #pragma unroll
  for (int k=0;k<8;++k){
    int e = l*8 + k;
    float t = (f[k]-mean)*rstd*g[e] + be[e];
    float gl = 0.5f*t*(1.f + erff(t*0.70710678118654752f));
    u16 b = f2bf(gl);
    if (k&1) ob[k>>1] |= (u32)b << 16; else ob[k>>1] = (u32)b;
  }
  uint4 o4 = {ob[0],ob[1],ob[2],ob[3]};
  *(uint4*)&hr[l*8] = o4;
}

// ---------------- launch ----------------
extern "C" void kernel_launch(void* const* d_in, const int* in_sizes, int n_in,
                              void* d_out, int out_size, void* d_ws, size_t ws_size,
                              hipStream_t stream)
{
  const float* x0  = (const float*)d_in[0];
  const float* x1  = (const float*)d_in[1];
  const float* Wqk = (const float*)d_in[2];
  const float* bqk = (const float*)d_in[3];
  const float* Wv  = (const float*)d_in[4];
  const float* bv  = (const float*)d_in[5];
  const float* Wo  = (const float*)d_in[6];
  const float* bo  = (const float*)d_in[7];
  const float* W1  = (const float*)d_in[8];
  const float* b1  = (const float*)d_in[9];
  const float* gln = (const float*)d_in[10];
  const float* bln = (const float*)d_in[11];
  const float* W2  = (const float*)d_in[12];
  const float* b2  = (const float*)d_in[13];
  (void)in_sizes; (void)n_in; (void)out_size; (void)ws_size;
  float* out = (float*)d_out;
  char* ws = (char*)d_ws;
  size_t off = 0;
  auto alloc = [&](size_t bytes)->void*{
    void* p = ws + off; off += (bytes + 255) & ~(size_t)255; return p; };
  u16* xc0 = (u16*)alloc((size_t)8192*512*2);   // [m][512]: cols 0..255 = x, 256..511 = mo
  u16* xc1 = (u16*)alloc((size_t)8192*512*2);
  u16* Wqkv= (u16*)alloc((size_t)512*256*2);
  u16* WoB = (u16*)alloc((size_t)256*256*2);
  u16* W1B = (u16*)alloc((size_t)512*512*2);
  u16* W2B = (u16*)alloc((size_t)256*512*2);
  u16* qk0 = (u16*)alloc((size_t)16*2048*64*2); // [bh][n][d], pre-scaled by D^-0.25
  u16* qk1 = (u16*)alloc((size_t)16*2048*64*2);
  u16* v0  = (u16*)alloc((size_t)16*2048*64*2);
  u16* v1  = (u16*)alloc((size_t)16*2048*64*2);
  u16* vT0 = (u16*)alloc((size_t)16*2048*64*2); // [bh][d][n]
  u16* vT1 = (u16*)alloc((size_t)16*2048*64*2);
  u16* m0  = (u16*)alloc((size_t)8192*256*2);
  u16* m1  = (u16*)alloc((size_t)8192*256*2);
  u16* h0  = (u16*)alloc((size_t)8192*512*2);
  u16* h1  = (u16*)alloc((size_t)8192*512*2);
  float* rm0 = (float*)alloc((size_t)16*2048*4);
  float* rs0 = (float*)alloc((size_t)16*2048*4);
  float* rm1 = (float*)alloc((size_t)16*2048*4);
  float* rs1 = (float*)alloc((size_t)16*2048*4);

  cast_x_k<<<dim3(512,2), 256, 0, stream>>>(x0, x1, xc0, xc1);
  cast_w_k<<<dim3(256), 256, 0, stream>>>(Wqk, Wv, Wo, W1, W2, Wqkv, WoB, W1B, W2B);
  gemm_k<0,256,512,4><<<dim3(64,4,2), 256, 0, stream>>>(
      xc0, xc1, Wqkv, bqk, bv, qk0, qk1, v0, v1, nullptr, nullptr, nullptr);
  transp_k<<<dim3(32,16,2), 256, 0, stream>>>(v0, v1, vT0, vT1);
  stats_k<<<dim3(16,16,2), 256, 0, stream>>>(qk0, qk1, rm0, rs0, rm1, rs1);
  attn_k<<<dim3(16,16,2), 256, 0, stream>>>(
      qk0, qk1, vT0, vT1, rm0, rs0, rm1, rs1, m0, m1, out);
  gemm_k<1,256,256,2><<<dim3(64,2,2), 256, 0, stream>>>(
      m0, m1, WoB, bo, nullptr, xc0, xc1, nullptr, nullptr, nullptr, nullptr, nullptr);
  gemm_k<2,512,512,4><<<dim3(64,4,2), 256, 0, stream>>>(
      xc0, xc1, W1B, b1, nullptr, h0, h1, nullptr, nullptr, nullptr, nullptr, nullptr);
  ln_gelu_k<<<dim3(2048,2), 256, 0, stream>>>(h0, h1, gln, bln);
  gemm_k<3,512,512,2><<<dim3(64,2,2), 256, 0, stream>>>(
      h0, h1, W2B, b2, nullptr, nullptr, nullptr, nullptr, nullptr, x0, x1, out);
}

// Round 2
// 425.331 us; speedup vs baseline: 1.0214x; 1.0214x over previous
//
#include <hip/hip_runtime.h>

// CrossBlock: two-stream cross-attention + gated FFN, MI355X (gfx950).
// bf16 MFMA (16x16x32), f32 accumulate. sim is computed once for BOTH softmax
// stat directions (row stats online + per-i-tile column partials merged by a
// tiny kernel); attn01/attn10 written exactly once, nontemporal, never re-read.

typedef unsigned short u16;
typedef unsigned int u32;
typedef __bf16 bf16x8 __attribute__((ext_vector_type(8)));
typedef float f32x4 __attribute__((ext_vector_type(4)));

#define DEV static __device__ __forceinline__

constexpr float MULT_ = 0.35355339059327373f;   // 64^-0.25
constexpr float L2E_  = 1.4426950408889634f;    // log2(e)

DEV u16 f2bf(float f){ __bf16 h = (__bf16)f; return __builtin_bit_cast(u16, h); }
DEV float bf2f(u16 h){ return __builtin_bit_cast(float, (u32)h << 16); }

DEV f32x4 mfma16(bf16x8 a, bf16x8 b, f32x4 c){
  return __builtin_amdgcn_mfma_f32_16x16x32_bf16(a, b, c, 0, 0, 0);
}

// barrier that does NOT drain vmcnt: lets prefetch loads / attn stores stay in
// flight. Safe here: the only undrained VMEM ops are loads into private regs
// and stores to write-only global buffers. (m201-verified pattern.)
DEV void barrier_ndv(){
  asm volatile("s_waitcnt lgkmcnt(0)" ::: "memory");
  __builtin_amdgcn_s_barrier();
  asm volatile("" ::: "memory");
}

// ---------------- casts ----------------
__global__ __launch_bounds__(256) void cast_x_k(
    const float* __restrict__ x0, const float* __restrict__ x1,
    u16* __restrict__ xc0, u16* __restrict__ xc1)
{
  const float* x = blockIdx.y ? x1 : x0;
  u16* xc = blockIdx.y ? xc1 : xc0;
  int gs = gridDim.x * blockDim.x;
  for (int v = blockIdx.x*blockDim.x + threadIdx.x; v < 8192*64; v += gs){
    float4 f = ((const float4*)x)[v];
    int m = v >> 6, e4 = (v & 63) << 2;
    ushort4 o;
    o.x = f2bf(f.x); o.y = f2bf(f.y); o.z = f2bf(f.z); o.w = f2bf(f.w);
    *(ushort4*)&xc[(size_t)m*512 + e4] = o;   // xcat cols 0..255 = x
  }
}

__global__ __launch_bounds__(256) void cast_w_k(
    const float* __restrict__ Wqk, const float* __restrict__ Wv,
    const float* __restrict__ Wo,  const float* __restrict__ W1,
    const float* __restrict__ W2,
    u16* __restrict__ Wqkv, u16* __restrict__ WoB,
    u16* __restrict__ W1B,  u16* __restrict__ W2B)
{
  int gs = gridDim.x * blockDim.x;
  int t0 = blockIdx.x*blockDim.x + threadIdx.x;
  for (int t = t0; t < 512*256; t += gs)
    Wqkv[t] = f2bf(t < 65536 ? Wqk[t] : Wv[t - 65536]);
  for (int t = t0; t < 256*256; t += gs) WoB[t] = f2bf(Wo[t]);
  for (int t = t0; t < 512*512; t += gs) W1B[t] = f2bf(W1[t]);
  for (int t = t0; t < 256*512; t += gs) W2B[t] = f2bf(W2[t]);
}

// ---------------- generic 128x128 MFMA GEMM: C = A[M,K] * Bw[N,K]^T ----------------
template<int EPI, int K, int LDA, int NB>
__global__ __launch_bounds__(256) void gemm_k(
    const u16* __restrict__ A0, const u16* __restrict__ A1,
    const u16* __restrict__ Bw,
    const float* __restrict__ bias, const float* __restrict__ bias2,
    u16* __restrict__ O0, u16* __restrict__ O1,
    u16* __restrict__ P0, u16* __restrict__ P1,
    const float* __restrict__ R0, const float* __restrict__ R1,
    float* __restrict__ Y)
{
  constexpr int LSA = 40;                       // 32 + 8 pad -> 2-way (free) LDS reads
  __shared__ u16 As[128*LSA], Bs[128*LSA];
  const int tid = threadIdx.x, w = tid>>6, l = tid&63;
  const int s = blockIdx.z;
  const u16* A = s ? A1 : A0;
  const int m0 = blockIdx.x*128, n0 = blockIdx.y*128;
  const int wr = (w>>1)*64, wc = (w&1)*64;
  const f32x4 z4 = {0.f,0.f,0.f,0.f};
  f32x4 acc[4][4];
  #pragma unroll
  for (int i=0;i<4;++i)
    #pragma unroll
    for (int j=0;j<4;++j) acc[i][j] = z4;
  const int srow = tid>>2, scol = (tid&3)*8;
  for (int kt = 0; kt < K; kt += 32){
    __syncthreads();
    #pragma unroll
    for (int r = 0; r < 2; ++r){
      int row = r*64 + srow;
      *(uint4*)&As[row*LSA + scol] = *(const uint4*)&A[(size_t)(m0+row)*LDA + kt + scol];
      *(uint4*)&Bs[row*LSA + scol] = *(const uint4*)&Bw[(size_t)(n0+row)*K + kt + scol];
    }
    __syncthreads();
    bf16x8 af[4], bfr[4];
    #pragma unroll
    for (int mf=0; mf<4; ++mf)
      af[mf] = *(const bf16x8*)&As[(wr+mf*16+(l&15))*LSA + (l>>4)*8];
    #pragma unroll
    for (int nf=0; nf<4; ++nf)
      bfr[nf] = *(const bf16x8*)&Bs[(wc+nf*16+(l&15))*LSA + (l>>4)*8];
    #pragma unroll
    for (int mf=0; mf<4; ++mf)
      #pragma unroll
      for (int nf=0; nf<4; ++nf)
        acc[mf][nf] = mfma16(af[mf], bfr[nf], acc[mf][nf]);
  }
  u16* Oq = s ? O1 : O0;
  u16* Ov = s ? P1 : P0;
  const float* R = s ? R1 : R0;
  #pragma unroll
  for (int mf=0; mf<4; ++mf){
    #pragma unroll
    for (int nf=0; nf<4; ++nf){
      #pragma unroll
      for (int r=0; r<4; ++r){
        int row = m0 + wr + mf*16 + (l>>4)*4 + r;   // M index (C/D layout, m89-verified)
        int col = n0 + wc + nf*16 + (l&15);         // N index
        float v = acc[mf][nf][r];
        if constexpr (EPI==0){
          int bb = row >> 11, n = row & 2047;
          if (col < 256){
            float q = (v + bias[col]) * MULT_;
            int hh = col >> 6, d = col & 63;
            Oq[(size_t)((bb*4+hh)*2048 + n)*64 + d] = f2bf(q);
          } else {
            int c2 = col - 256;
            int hh = c2 >> 6, d = c2 & 63;
            Ov[(size_t)((bb*4+hh)*2048 + n)*64 + d] = f2bf(v + bias2[c2]);
          }
        } else if constexpr (EPI==1){
          Oq[(size_t)row*512 + 256 + col] = f2bf(v + bias[col]);
        } else if constexpr (EPI==2){
          Oq[(size_t)row*512 + col] = f2bf(v + bias[col]);
        } else {
          float* Yp = Y + (size_t)s*2097152;
          Yp[(size_t)row*256 + col] = v + bias[col] + R[(size_t)row*256 + col];
        }
      }
    }
  }
}

// ---------------- v[bh][n][d] -> vT[bh][d][n] ----------------
__global__ __launch_bounds__(256) void transp_k(
    const u16* __restrict__ v0, const u16* __restrict__ v1,
    u16* __restrict__ t0p, u16* __restrict__ t1p)
{
  __shared__ u16 t[64*66];
  const u16* vin = blockIdx.z ? v1 : v0;
  u16* vout = blockIdx.z ? t1p : t0p;
  int bh = blockIdx.y, j0 = blockIdx.x*64, tid = threadIdx.x;
  #pragma unroll
  for (int r=0;r<2;++r){
    int j = r*32 + (tid>>3), d = (tid&7)*8;
    *(uint4*)&t[j*66 + d] = *(const uint4*)&vin[((size_t)bh*2048 + j0 + j)*64 + d];
  }
  __syncthreads();
  #pragma unroll
  for (int r=0;r<2;++r){
    int d = r*32 + (tid>>3), j8 = (tid&7)*8;
    u32 p[4];
    #pragma unroll
    for (int k=0;k<4;++k){
      u32 lo = t[(j8+2*k)*66 + d];
      u32 hi = t[(j8+2*k+1)*66 + d];
      p[k] = lo | (hi<<16);
    }
    uint4 o = {p[0],p[1],p[2],p[3]};
    *(uint4*)&vout[((size_t)bh*64 + d)*2048 + j0 + j8] = o;
  }
}

// ---------------- dual softmax stats from ONE sim pass ----------------
// S[i][j] = qk0[i]·qk1[j]. Row (i) stats -> rm0/rs0 (online). Column (j)
// partials over this WG's 128 rows -> pmax/psum[bh][it][j], merged by colreduce_k.
__global__ __launch_bounds__(256) void stats2_k(
    const u16* __restrict__ qk0, const u16* __restrict__ qk1,
    float* __restrict__ rm0, float* __restrict__ rs0,
    float* __restrict__ pmax, float* __restrict__ psum)
{
  __shared__ u16 Ks[128*72];
  __shared__ float cmaxw[4*128], csumw[4*128];
  const int bh = blockIdx.y, i0 = blockIdx.x*128;
  const int tid = threadIdx.x, w = tid>>6, l = tid&63;
  const u16* Qb = qk0 + (size_t)bh*2048*64;
  const u16* Kb = qk1 + (size_t)bh*2048*64;
  bf16x8 qf[2][2];
  #pragma unroll
  for (int mf=0; mf<2; ++mf)
    #pragma unroll
    for (int kf=0; kf<2; ++kf)
      qf[mf][kf] = *(const bf16x8*)&Qb[(size_t)(i0 + w*32 + mf*16 + (l&15))*64 + kf*32 + (l>>4)*8];
  float rmv[2][4], rlv[2][4];
  #pragma unroll
  for (int mf=0;mf<2;++mf)
    #pragma unroll
    for (int r=0;r<4;++r){ rmv[mf][r] = -3.0e38f; rlv[mf][r] = 0.f; }
  const int krow = tid>>3, kc = (tid&7)*8;
  uint4 kreg[4];
  #pragma unroll
  for (int r=0;r<4;++r)
    kreg[r] = *(const uint4*)&Kb[(size_t)(r*32+krow)*64 + kc];
  const f32x4 z4 = {0.f,0.f,0.f,0.f};
  for (int jt=0; jt<2048; jt+=128){
    barrier_ndv();                       // Ks + cmaxw/csumw free
    #pragma unroll
    for (int r=0;r<4;++r) *(uint4*)&Ks[(r*32+krow)*72 + kc] = kreg[r];
    if (jt+128 < 2048){
      #pragma unroll
      for (int r=0;r<4;++r)
        kreg[r] = *(const uint4*)&Kb[(size_t)(jt+128+r*32+krow)*64 + kc];
    }
    barrier_ndv();                       // Ks ready
    f32x4 acc[2][8];
    #pragma unroll
    for (int mf=0;mf<2;++mf)
      #pragma unroll
      for (int nf=0;nf<8;++nf) acc[mf][nf] = z4;
    #pragma unroll
    for (int nf=0; nf<8; ++nf){
      bf16x8 b0 = *(const bf16x8*)&Ks[(nf*16+(l&15))*72 + (l>>4)*8];
      bf16x8 b1 = *(const bf16x8*)&Ks[(nf*16+(l&15))*72 + 32 + (l>>4)*8];
      acc[0][nf] = mfma16(qf[0][0], b0, acc[0][nf]);
      acc[0][nf] = mfma16(qf[0][1], b1, acc[0][nf]);
      acc[1][nf] = mfma16(qf[1][0], b0, acc[1][nf]);
      acc[1][nf] = mfma16(qf[1][1], b1, acc[1][nf]);
    }
    // row stats (direction 0), online
    #pragma unroll
    for (int mf=0; mf<2; ++mf)
      #pragma unroll
      for (int r=0; r<4; ++r){
        float tm = acc[mf][0][r];
        #pragma unroll
        for (int nf=1; nf<8; ++nf) tm = fmaxf(tm, acc[mf][nf][r]);
        tm = fmaxf(tm, __shfl_xor(tm, 1));
        tm = fmaxf(tm, __shfl_xor(tm, 2));
        tm = fmaxf(tm, __shfl_xor(tm, 4));
        tm = fmaxf(tm, __shfl_xor(tm, 8));
        float nm = fmaxf(rmv[mf][r], tm);
        float ps = 0.f;
        #pragma unroll
        for (int nf=0; nf<8; ++nf) ps += exp2f((acc[mf][nf][r]-nm)*L2E_);
        ps += __shfl_xor(ps, 1);
        ps += __shfl_xor(ps, 2);
        ps += __shfl_xor(ps, 4);
        ps += __shfl_xor(ps, 8);
        rlv[mf][r] = rlv[mf][r]*exp2f((rmv[mf][r]-nm)*L2E_) + ps;
        rmv[mf][r] = nm;
      }
    // column partials (direction 1): per-wave 32-row (max, sumexp) per column
    float cm[8], cs[8];
    #pragma unroll
    for (int nf=0; nf<8; ++nf){
      float m = acc[0][nf][0];
      #pragma unroll
      for (int r=1;r<4;++r) m = fmaxf(m, acc[0][nf][r]);
      #pragma unroll
      for (int r=0;r<4;++r) m = fmaxf(m, acc[1][nf][r]);
      m = fmaxf(m, __shfl_xor(m, 16));
      m = fmaxf(m, __shfl_xor(m, 32));
      float s = 0.f;
      #pragma unroll
      for (int mf=0;mf<2;++mf)
        #pragma unroll
        for (int r=0;r<4;++r) s += exp2f((acc[mf][nf][r]-m)*L2E_);
      s += __shfl_xor(s, 16);
      s += __shfl_xor(s, 32);
      cm[nf] = m; cs[nf] = s;
    }
    if (l < 16){
      #pragma unroll
      for (int nf=0; nf<8; ++nf){
        cmaxw[w*128 + nf*16 + l] = cm[nf];
        csumw[w*128 + nf*16 + l] = cs[nf];
      }
    }
    barrier_ndv();                       // partials in LDS
    if (tid < 128){
      float m = cmaxw[tid];
      #pragma unroll
      for (int ww=1; ww<4; ++ww) m = fmaxf(m, cmaxw[ww*128 + tid]);
      float s = 0.f;
      #pragma unroll
      for (int ww=0; ww<4; ++ww)
        s += csumw[ww*128 + tid] * exp2f((cmaxw[ww*128 + tid]-m)*L2E_);
      size_t o = ((size_t)bh*16 + blockIdx.x)*2048 + jt + tid;
      pmax[o] = m; psum[o] = s;
    }
  }
  if ((l&15)==0){
    #pragma unroll
    for (int mf=0;mf<2;++mf)
      #pragma unroll
      for (int r=0;r<4;++r){
        int i = i0 + w*32 + mf*16 + (l>>4)*4 + r;
        rm0[bh*2048 + i] = rmv[mf][r];
        rs0[bh*2048 + i] = rlv[mf][r];
      }
  }
}

// merge the 16 per-i-tile column partials -> rm1/rs1
__global__ __launch_bounds__(256) void colreduce_k(
    const float* __restrict__ pmax, const float* __restrict__ psum,
    float* __restrict__ rm1, float* __restrict__ rs1)
{
  int idx = blockIdx.x*256 + threadIdx.x;   // 16*2048
  int bh = idx >> 11, j = idx & 2047;
  float pm[16], ps[16];
  #pragma unroll
  for (int it=0; it<16; ++it){
    size_t o = ((size_t)bh*16 + it)*2048 + j;
    pm[it] = pmax[o]; ps[it] = psum[o];
  }
  float m = pm[0];
  #pragma unroll
  for (int it=1; it<16; ++it) m = fmaxf(m, pm[it]);
  float s = 0.f;
  #pragma unroll
  for (int it=0; it<16; ++it) s += ps[it] * exp2f((pm[it]-m)*L2E_);
  rm1[bh*2048 + j] = m;
  rs1[bh*2048 + j] = s;
}

// ---------------- fused: recompute sim tile, write attn rows (nt), P*V ----------------
__global__ __launch_bounds__(256) void attn_k(
    const u16* __restrict__ qk0, const u16* __restrict__ qk1,
    const u16* __restrict__ vT0, const u16* __restrict__ vT1,
    const float* __restrict__ rm0, const float* __restrict__ rs0,
    const float* __restrict__ rm1, const float* __restrict__ rs1,
    u16* __restrict__ mo0, u16* __restrict__ mo1,
    float* __restrict__ dout)
{
  __shared__ u16 Ks[128*72];
  __shared__ u16 Vs[64*136];
  __shared__ u16 Ps[128*136];
  const int z = blockIdx.z;
  const u16* Q  = z ? qk1 : qk0;
  const u16* Kp = z ? qk0 : qk1;
  const u16* Vp = z ? vT0 : vT1;
  const float* rm = z ? rm1 : rm0;
  const float* rs = z ? rs1 : rs0;
  u16* mo = z ? mo1 : mo0;
  const int bh = blockIdx.y, i0 = blockIdx.x*128;
  float* aout = dout + (size_t)(z ? 71303168u : 4194304u) + (size_t)bh*4194304u;
  const int tid = threadIdx.x, w = tid>>6, l = tid&63;
  const u16* Qb = Q + (size_t)bh*2048*64;
  const u16* Kb = Kp + (size_t)bh*2048*64;
  const u16* Vb = Vp + (size_t)bh*64*2048;
  bf16x8 qf[2][2];
  #pragma unroll
  for (int mf=0; mf<2; ++mf)
    #pragma unroll
    for (int kf=0; kf<2; ++kf)
      qf[mf][kf] = *(const bf16x8*)&Qb[(size_t)(i0 + w*32 + mf*16 + (l&15))*64 + kf*32 + (l>>4)*8];
  float rmr[2][4], rir[2][4];
  #pragma unroll
  for (int mf=0;mf<2;++mf)
    #pragma unroll
    for (int r=0;r<4;++r){
      int i = i0 + w*32 + mf*16 + (l>>4)*4 + r;
      rmr[mf][r] = rm[bh*2048 + i];
      rir[mf][r] = 1.f / rs[bh*2048 + i];
    }
  const f32x4 z4 = {0.f,0.f,0.f,0.f};
  f32x4 macc[2][4];
  #pragma unroll
  for (int mf=0;mf<2;++mf)
    #pragma unroll
    for (int nf=0;nf<4;++nf) macc[mf][nf] = z4;
  const int krow = tid>>3, kc = (tid&7)*8;
  const int vd = tid>>4, vc = (tid&15)*8;
  uint4 kreg[4], vreg[4];
  #pragma unroll
  for (int r=0;r<4;++r){
    kreg[r] = *(const uint4*)&Kb[(size_t)(r*32+krow)*64 + kc];
    vreg[r] = *(const uint4*)&Vb[(size_t)(r*16+vd)*2048 + vc];
  }
  for (int jt=0; jt<2048; jt+=128){
    barrier_ndv();                       // prev PV done: Ks/Vs/Ps free
    #pragma unroll
    for (int r=0;r<4;++r) *(uint4*)&Ks[(r*32+krow)*72 + kc] = kreg[r];
    #pragma unroll
    for (int r=0;r<4;++r) *(uint4*)&Vs[(r*16+vd)*136 + vc] = vreg[r];
    if (jt+128 < 2048){
      #pragma unroll
      for (int r=0;r<4;++r){
        kreg[r] = *(const uint4*)&Kb[(size_t)(jt+128+r*32+krow)*64 + kc];
        vreg[r] = *(const uint4*)&Vb[(size_t)(r*16+vd)*2048 + jt+128 + vc];
      }
    }
    barrier_ndv();                       // Ks/Vs ready
    f32x4 acc[2][8];
    #pragma unroll
    for (int mf=0;mf<2;++mf)
      #pragma unroll
      for (int nf=0;nf<8;++nf) acc[mf][nf] = z4;
    #pragma unroll
    for (int nf=0; nf<8; ++nf){
      bf16x8 b0 = *(const bf16x8*)&Ks[(nf*16+(l&15))*72 + (l>>4)*8];
      bf16x8 b1 = *(const bf16x8*)&Ks[(nf*16+(l&15))*72 + 32 + (l>>4)*8];
      acc[0][nf] = mfma16(qf[0][0], b0, acc[0][nf]);
      acc[0][nf] = mfma16(qf[0][1], b1, acc[0][nf]);
      acc[1][nf] = mfma16(qf[1][0], b0, acc[1][nf]);
      acc[1][nf] = mfma16(qf[1][1], b1, acc[1][nf]);
    }
    #pragma unroll
    for (int mf=0;mf<2;++mf)
      #pragma unroll
      for (int nf=0;nf<8;++nf){
        int coll = nf*16 + (l&15);
        #pragma unroll
        for (int r=0;r<4;++r){
          int rowl = w*32 + mf*16 + (l>>4)*4 + r;
          float p = exp2f((acc[mf][nf][r]-rmr[mf][r])*L2E_) * rir[mf][r];
          __builtin_nontemporal_store(p, &aout[(size_t)(i0+rowl)*2048 + jt + coll]);
          Ps[rowl*136 + coll] = f2bf(p);
        }
      }
    barrier_ndv();                       // Ps ready
    #pragma unroll
    for (int kf=0; kf<4; ++kf){
      bf16x8 pa0 = *(const bf16x8*)&Ps[(w*32 + (l&15))*136 + kf*32 + (l>>4)*8];
      bf16x8 pa1 = *(const bf16x8*)&Ps[(w*32 + 16 + (l&15))*136 + kf*32 + (l>>4)*8];
      #pragma unroll
      for (int nf=0; nf<4; ++nf){
        bf16x8 vb = *(const bf16x8*)&Vs[(nf*16+(l&15))*136 + kf*32 + (l>>4)*8];
        macc[0][nf] = mfma16(pa0, vb, macc[0][nf]);
        macc[1][nf] = mfma16(pa1, vb, macc[1][nf]);
      }
    }
  }
  int bb = bh>>2, hh = bh&3;
  #pragma unroll
  for (int mf=0;mf<2;++mf)
    #pragma unroll
    for (int nf=0;nf<4;++nf)
      #pragma unroll
      for (int r=0;r<4;++r){
        int n = i0 + w*32 + mf*16 + (l>>4)*4 + r;
        int d = nf*16 + (l&15);
        mo[(size_t)(bb*2048 + n)*256 + hh*64 + d] = f2bf(macc[mf][nf][r]);
      }
}

// ---------------- LayerNorm + exact GELU, in place on h[8192][512] ----------------
__global__ __launch_bounds__(256) void ln_gelu_k(
    u16* __restrict__ h0, u16* __restrict__ h1,
    const float* __restrict__ g, const float* __restrict__ be)
{
  u16* h = blockIdx.y ? h1 : h0;
  int row = blockIdx.x*4 + (threadIdx.x>>6);
  int l = threadIdx.x & 63;
  u16* hr = h + (size_t)row*512;
  uint4 raw = *(const uint4*)&hr[l*8];
  u32 ua[4] = {raw.x, raw.y, raw.z, raw.w};
  float f[8];
  #pragma unroll
  for (int k=0;k<4;++k){
    f[2*k]   = bf2f((u16)(ua[k] & 0xFFFFu));
    f[2*k+1] = bf2f((u16)(ua[k] >> 16));
  }
  float s = 0.f, s2 = 0.f;
  #pragma unroll
  for (int k=0;k<8;++k){ s += f[k]; s2 += f[k]*f[k]; }
  #pragma unroll
  for (int o=1;o<64;o<<=1){ s += __shfl_xor(s,o); s2 += __shfl_xor(s2,o); }
  float mean = s * (1.f/512.f);
  float var  = s2 * (1.f/512.f) - mean*mean;
  float rstd = rsqrtf(var + 1e-5f);
  u32 ob[4];
  #pragma unroll
  for (int k=0;k<8;++k){
    int e = l*8 + k;
    float t = (f[k]-mean)*rstd*g[e] + be[e];
    float gl = 0.5f*t*(1.f + erff(t*0.70710678118654752f));
    u16 b = f2bf(gl);
    if (k&1) ob[k>>1] |= (u32)b << 16; else ob[k>>1] = (u32)b;
  }
  uint4 o4 = {ob[0],ob[1],ob[2],ob[3]};
  *(uint4*)&hr[l*8] = o4;
}

// ---------------- launch ----------------
extern "C" void kernel_launch(void* const* d_in, const int* in_sizes, int n_in,
                              void* d_out, int out_size, void* d_ws, size_t ws_size,
                              hipStream_t stream)
{
  const float* x0  = (const float*)d_in[0];
  const float* x1  = (const float*)d_in[1];
  const float* Wqk = (const float*)d_in[2];
  const float* bqk = (const float*)d_in[3];
  const float* Wv  = (const float*)d_in[4];
  const float* bv  = (const float*)d_in[5];
  const float* Wo  = (const float*)d_in[6];
  const float* bo  = (const float*)d_in[7];
  const float* W1  = (const float*)d_in[8];
  const float* b1  = (const float*)d_in[9];
  const float* gln = (const float*)d_in[10];
  const float* bln = (const float*)d_in[11];
  const float* W2  = (const float*)d_in[12];
  const float* b2  = (const float*)d_in[13];
  (void)in_sizes; (void)n_in; (void)out_size; (void)ws_size;
  float* out = (float*)d_out;
  char* ws = (char*)d_ws;
  size_t off = 0;
  auto alloc = [&](size_t bytes)->void*{
    void* p = ws + off; off += (bytes + 255) & ~(size_t)255; return p; };
  u16* xc0 = (u16*)alloc((size_t)8192*512*2);   // [m][512]: cols 0..255 = x, 256..511 = mo
  u16* xc1 = (u16*)alloc((size_t)8192*512*2);
  u16* Wqkv= (u16*)alloc((size_t)512*256*2);
  u16* WoB = (u16*)alloc((size_t)256*256*2);
  u16* W1B = (u16*)alloc((size_t)512*512*2);
  u16* W2B = (u16*)alloc((size_t)256*512*2);
  u16* qk0 = (u16*)alloc((size_t)16*2048*64*2); // [bh][n][d], pre-scaled by D^-0.25
  u16* qk1 = (u16*)alloc((size_t)16*2048*64*2);
  u16* v0  = (u16*)alloc((size_t)16*2048*64*2);
  u16* v1  = (u16*)alloc((size_t)16*2048*64*2);
  u16* vT0 = (u16*)alloc((size_t)16*2048*64*2); // [bh][d][n]
  u16* vT1 = (u16*)alloc((size_t)16*2048*64*2);
  u16* m0  = (u16*)alloc((size_t)8192*256*2);
  u16* m1  = (u16*)alloc((size_t)8192*256*2);
  u16* h0  = (u16*)alloc((size_t)8192*512*2);
  u16* h1  = (u16*)alloc((size_t)8192*512*2);
  float* rm0 = (float*)alloc((size_t)16*2048*4);
  float* rs0 = (float*)alloc((size_t)16*2048*4);
  float* rm1 = (float*)alloc((size_t)16*2048*4);
  float* rs1 = (float*)alloc((size_t)16*2048*4);
  float* pmax = (float*)alloc((size_t)16*16*2048*4);
  float* psum = (float*)alloc((size_t)16*16*2048*4);

  cast_x_k<<<dim3(512,2), 256, 0, stream>>>(x0, x1, xc0, xc1);
  cast_w_k<<<dim3(256), 256, 0, stream>>>(Wqk, Wv, Wo, W1, W2, Wqkv, WoB, W1B, W2B);
  gemm_k<0,256,512,4><<<dim3(64,4,2), 256, 0, stream>>>(
      xc0, xc1, Wqkv, bqk, bv, qk0, qk1, v0, v1, nullptr, nullptr, nullptr);
  transp_k<<<dim3(32,16,2), 256, 0, stream>>>(v0, v1, vT0, vT1);
  stats2_k<<<dim3(16,16), 256, 0, stream>>>(qk0, qk1, rm0, rs0, pmax, psum);
  colreduce_k<<<dim3(128), 256, 0, stream>>>(pmax, psum, rm1, rs1);
  attn_k<<<dim3(16,16,2), 256, 0, stream>>>(
      qk0, qk1, vT0, vT1, rm0, rs0, rm1, rs1, m0, m1, out);
  gemm_k<1,256,256,2><<<dim3(64,2,2), 256, 0, stream>>>(
      m0, m1, WoB, bo, nullptr, xc0, xc1, nullptr, nullptr, nullptr, nullptr, nullptr);
  gemm_k<2,512,512,4><<<dim3(64,4,2), 256, 0, stream>>>(
      xc0, xc1, W1B, b1, nullptr, h0, h1, nullptr, nullptr, nullptr, nullptr, nullptr);
  ln_gelu_k<<<dim3(2048,2), 256, 0, stream>>>(h0, h1, gln, bln);
  gemm_k<3,512,512,2><<<dim3(64,2,2), 256, 0, stream>>>(
      h0, h1, W2B, b2, nullptr, nullptr, nullptr, nullptr, nullptr, x0, x1, out);
}

// Round 3
// 388.375 us; speedup vs baseline: 1.1186x; 1.0952x over previous
//
#include <hip/hip_runtime.h>

// CrossBlock: two-stream cross-attention + gated FFN, MI355X (gfx950).
// bf16 MFMA (16x16x32), f32 accumulate. sim computed once for BOTH softmax
// directions (stats2 + reduce); attn written once, nontemporal, never re-read.
// GEMMs use global_load_lds (w=16) staging, m97 structure. qk pre-scaled by
// D^-0.25 * sqrt(log2 e) so softmax runs in exp2 domain with no per-elem mul.

typedef unsigned short u16;
typedef unsigned int u32;
typedef __bf16 bf16x8 __attribute__((ext_vector_type(8)));
typedef float f32x4 __attribute__((ext_vector_type(4)));

#define DEV static __device__ __forceinline__

constexpr float MULT2_ = 0.42466090013685146f;  // 64^-0.25 * sqrt(log2(e))

DEV u16 f2bf(float f){ __bf16 h = (__bf16)f; return __builtin_bit_cast(u16, h); }
DEV float bf2f(u16 h){ return __builtin_bit_cast(float, (u32)h << 16); }

DEV f32x4 mfma16(bf16x8 a, bf16x8 b, f32x4 c){
  return __builtin_amdgcn_mfma_f32_16x16x32_bf16(a, b, c, 0, 0, 0);
}

// barrier that does NOT drain vmcnt (prefetch loads / nt stores stay in flight)
DEV void barrier_ndv(){
  asm volatile("s_waitcnt lgkmcnt(0)" ::: "memory");
  __builtin_amdgcn_s_barrier();
  asm volatile("" ::: "memory");
}

typedef const __attribute__((address_space(1))) void cvoid_g;
typedef __attribute__((address_space(3))) void void_l;
DEV void gload16(const void* g, void* l){
  __builtin_amdgcn_global_load_lds((cvoid_g*)g, (void_l*)l, 16, 0, 0);
}

// ---------------- casts ----------------
__global__ __launch_bounds__(256) void cast_x_k(
    const float* __restrict__ x0, const float* __restrict__ x1,
    u16* __restrict__ xc0, u16* __restrict__ xc1)
{
  const float* x = blockIdx.y ? x1 : x0;
  u16* xc = blockIdx.y ? xc1 : xc0;
  int gs = gridDim.x * blockDim.x;
  for (int v = blockIdx.x*blockDim.x + threadIdx.x; v < 8192*64; v += gs){
    float4 f = ((const float4*)x)[v];
    int m = v >> 6, e4 = (v & 63) << 2;
    ushort4 o;
    o.x = f2bf(f.x); o.y = f2bf(f.y); o.z = f2bf(f.z); o.w = f2bf(f.w);
    *(ushort4*)&xc[(size_t)m*512 + e4] = o;   // xcat cols 0..255 = x
  }
}

__global__ __launch_bounds__(256) void cast_w_k(
    const float* __restrict__ Wqk, const float* __restrict__ Wv,
    const float* __restrict__ Wo,  const float* __restrict__ W1,
    const float* __restrict__ W2,
    u16* __restrict__ Wqkv, u16* __restrict__ WoB,
    u16* __restrict__ W1B,  u16* __restrict__ W2B)
{
  int gs = gridDim.x * blockDim.x;
  int t0 = blockIdx.x*blockDim.x + threadIdx.x;
  for (int t = t0; t < 512*256; t += gs)
    Wqkv[t] = f2bf(t < 65536 ? Wqk[t] : Wv[t - 65536]);
  for (int t = t0; t < 256*256; t += gs) WoB[t] = f2bf(Wo[t]);
  for (int t = t0; t < 512*512; t += gs) W1B[t] = f2bf(W1[t]);
  for (int t = t0; t < 256*512; t += gs) W2B[t] = f2bf(W2[t]);
}

// ---------------- 128x128 MFMA GEMM, global_load_lds staging (m97 structure) ----
// C = A[M,K] * Bw[N,K]^T
template<int EPI, int K, int LDA>
__global__ __launch_bounds__(256) void gemm_k(
    const u16* __restrict__ A0, const u16* __restrict__ A1,
    const u16* __restrict__ Bw,
    const float* __restrict__ bias, const float* __restrict__ bias2,
    u16* __restrict__ O0, u16* __restrict__ O1,
    u16* __restrict__ P0, u16* __restrict__ P1,
    const float* __restrict__ R0, const float* __restrict__ R1,
    float* __restrict__ Y)
{
  __shared__ u16 As[128*32], Bs[128*32];   // linear, rows of 64 B
  const int tid = threadIdx.x, w = tid>>6, l = tid&63;
  const int s = blockIdx.z;
  const u16* A = s ? A1 : A0;
  const int m0 = blockIdx.x*128, n0 = blockIdx.y*128;
  const int wr = (w>>1)*64, wc = (w&1)*64;
  const f32x4 z4 = {0.f,0.f,0.f,0.f};
  f32x4 acc[4][4];
  #pragma unroll
  for (int i=0;i<4;++i)
    #pragma unroll
    for (int j=0;j<4;++j) acc[i][j] = z4;
  const int seg0 = w*2, seg1 = w*2+1;      // each wave stages 2 segs of A and B
  const int srow = l>>2, sc8 = (l&3)*8;    // 16 rows x 32 elems per 1KB segment
  for (int kt = 0; kt < K; kt += 32){
    barrier_ndv();                          // prev ds_reads done; LDS free
    gload16(&A [(size_t)(m0+seg0*16+srow)*LDA + kt + sc8], &As[seg0*512]);
    gload16(&A [(size_t)(m0+seg1*16+srow)*LDA + kt + sc8], &As[seg1*512]);
    gload16(&Bw[(size_t)(n0+seg0*16+srow)*K   + kt + sc8], &Bs[seg0*512]);
    gload16(&Bw[(size_t)(n0+seg1*16+srow)*K   + kt + sc8], &Bs[seg1*512]);
    __syncthreads();                        // drains vmcnt -> LDS ready
    bf16x8 af[4], bfr[4];
    #pragma unroll
    for (int mf=0; mf<4; ++mf)
      af[mf] = *(const bf16x8*)&As[(wr+mf*16+(l&15))*32 + (l>>4)*8];
    #pragma unroll
    for (int nf=0; nf<4; ++nf)
      bfr[nf] = *(const bf16x8*)&Bs[(wc+nf*16+(l&15))*32 + (l>>4)*8];
    #pragma unroll
    for (int mf=0; mf<4; ++mf)
      #pragma unroll
      for (int nf=0; nf<4; ++nf)
        acc[mf][nf] = mfma16(af[mf], bfr[nf], acc[mf][nf]);
  }
  u16* Oq = s ? O1 : O0;
  u16* Ov = s ? P1 : P0;
  const float* R = s ? R1 : R0;
  #pragma unroll
  for (int mf=0; mf<4; ++mf){
    #pragma unroll
    for (int nf=0; nf<4; ++nf){
      #pragma unroll
      for (int r=0; r<4; ++r){
        int row = m0 + wr + mf*16 + (l>>4)*4 + r;   // M index (C/D layout, m89)
        int col = n0 + wc + nf*16 + (l&15);         // N index
        float v = acc[mf][nf][r];
        if constexpr (EPI==0){
          int bb = row >> 11, n = row & 2047;
          if (col < 256){
            float q = (v + bias[col]) * MULT2_;
            int hh = col >> 6, d = col & 63;
            Oq[(size_t)((bb*4+hh)*2048 + n)*64 + d] = f2bf(q);
          } else {
            int c2 = col - 256;
            int hh = c2 >> 6, d = c2 & 63;
            Ov[(size_t)((bb*4+hh)*2048 + n)*64 + d] = f2bf(v + bias2[c2]);
          }
        } else if constexpr (EPI==1){
          Oq[(size_t)row*512 + 256 + col] = f2bf(v + bias[col]);
        } else if constexpr (EPI==2){
          Oq[(size_t)row*512 + col] = f2bf(v + bias[col]);
        } else {
          float* Yp = Y + (size_t)s*2097152;
          Yp[(size_t)row*256 + col] = v + bias[col] + R[(size_t)row*256 + col];
        }
      }
    }
  }
}

// ---------------- v[bh][n][d] -> vT[bh][d][n] ----------------
__global__ __launch_bounds__(256) void transp_k(
    const u16* __restrict__ v0, const u16* __restrict__ v1,
    u16* __restrict__ t0p, u16* __restrict__ t1p)
{
  __shared__ u16 t[64*66];
  const u16* vin = blockIdx.z ? v1 : v0;
  u16* vout = blockIdx.z ? t1p : t0p;
  int bh = blockIdx.y, j0 = blockIdx.x*64, tid = threadIdx.x;
  #pragma unroll
  for (int r=0;r<2;++r){
    int j = r*32 + (tid>>3), d = (tid&7)*8;
    *(uint4*)&t[j*66 + d] = *(const uint4*)&vin[((size_t)bh*2048 + j0 + j)*64 + d];
  }
  __syncthreads();
  #pragma unroll
  for (int r=0;r<2;++r){
    int d = r*32 + (tid>>3), j8 = (tid&7)*8;
    u32 p[4];
    #pragma unroll
    for (int k=0;k<4;++k){
      u32 lo = t[(j8+2*k)*66 + d];
      u32 hi = t[(j8+2*k+1)*66 + d];
      p[k] = lo | (hi<<16);
    }
    uint4 o = {p[0],p[1],p[2],p[3]};
    *(uint4*)&vout[((size_t)bh*64 + d)*2048 + j0 + j8] = o;
  }
}

// ---------------- dual softmax stats from ONE sim pass (j-split grid) --------
// grid (it=16, jc=4, bh=16). Row partials per (i, jc); col partials per (it, j).
__global__ __launch_bounds__(256) void stats2_k(
    const u16* __restrict__ qk0, const u16* __restrict__ qk1,
    float* __restrict__ rpm, float* __restrict__ rps,
    float* __restrict__ pmax, float* __restrict__ psum)
{
  __shared__ u16 Ks[128*72];
  __shared__ float cmaxw[4*128], csumw[4*128];
  const int bh = blockIdx.z, i0 = blockIdx.x*128, j0 = blockIdx.y*512;
  const int tid = threadIdx.x, w = tid>>6, l = tid&63;
  const u16* Qb = qk0 + (size_t)bh*2048*64;
  const u16* Kb = qk1 + (size_t)bh*2048*64;
  bf16x8 qf[2][2];
  #pragma unroll
  for (int mf=0; mf<2; ++mf)
    #pragma unroll
    for (int kf=0; kf<2; ++kf)
      qf[mf][kf] = *(const bf16x8*)&Qb[(size_t)(i0 + w*32 + mf*16 + (l&15))*64 + kf*32 + (l>>4)*8];
  float rmv[2][4], rlv[2][4];
  #pragma unroll
  for (int mf=0;mf<2;++mf)
    #pragma unroll
    for (int r=0;r<4;++r){ rmv[mf][r] = -3.0e38f; rlv[mf][r] = 0.f; }
  const int krow = tid>>3, kc = (tid&7)*8;
  uint4 kreg[4];
  #pragma unroll
  for (int r=0;r<4;++r)
    kreg[r] = *(const uint4*)&Kb[(size_t)(j0+r*32+krow)*64 + kc];
  const f32x4 z4 = {0.f,0.f,0.f,0.f};
  for (int jt=j0; jt<j0+512; jt+=128){
    barrier_ndv();
    #pragma unroll
    for (int r=0;r<4;++r) *(uint4*)&Ks[(r*32+krow)*72 + kc] = kreg[r];
    if (jt+128 < j0+512){
      #pragma unroll
      for (int r=0;r<4;++r)
        kreg[r] = *(const uint4*)&Kb[(size_t)(jt+128+r*32+krow)*64 + kc];
    }
    barrier_ndv();
    f32x4 acc[2][8];
    #pragma unroll
    for (int mf=0;mf<2;++mf)
      #pragma unroll
      for (int nf=0;nf<8;++nf) acc[mf][nf] = z4;
    #pragma unroll
    for (int nf=0; nf<8; ++nf){
      bf16x8 b0 = *(const bf16x8*)&Ks[(nf*16+(l&15))*72 + (l>>4)*8];
      bf16x8 b1 = *(const bf16x8*)&Ks[(nf*16+(l&15))*72 + 32 + (l>>4)*8];
      acc[0][nf] = mfma16(qf[0][0], b0, acc[0][nf]);
      acc[0][nf] = mfma16(qf[0][1], b1, acc[0][nf]);
      acc[1][nf] = mfma16(qf[1][0], b0, acc[1][nf]);
      acc[1][nf] = mfma16(qf[1][1], b1, acc[1][nf]);
    }
    // row stats (dir 0), online, exp2 domain
    #pragma unroll
    for (int mf=0; mf<2; ++mf)
      #pragma unroll
      for (int r=0; r<4; ++r){
        float tm = acc[mf][0][r];
        #pragma unroll
        for (int nf=1; nf<8; ++nf) tm = fmaxf(tm, acc[mf][nf][r]);
        tm = fmaxf(tm, __shfl_xor(tm, 1));
        tm = fmaxf(tm, __shfl_xor(tm, 2));
        tm = fmaxf(tm, __shfl_xor(tm, 4));
        tm = fmaxf(tm, __shfl_xor(tm, 8));
        float nm = fmaxf(rmv[mf][r], tm);
        float ps = 0.f;
        #pragma unroll
        for (int nf=0; nf<8; ++nf) ps += exp2f(acc[mf][nf][r]-nm);
        ps += __shfl_xor(ps, 1);
        ps += __shfl_xor(ps, 2);
        ps += __shfl_xor(ps, 4);
        ps += __shfl_xor(ps, 8);
        rlv[mf][r] = rlv[mf][r]*exp2f(rmv[mf][r]-nm) + ps;
        rmv[mf][r] = nm;
      }
    // column partials (dir 1): 128-row (max, sumexp2) per column
    float cm[8], cs[8];
    #pragma unroll
    for (int nf=0; nf<8; ++nf){
      float m = acc[0][nf][0];
      #pragma unroll
      for (int r=1;r<4;++r) m = fmaxf(m, acc[0][nf][r]);
      #pragma unroll
      for (int r=0;r<4;++r) m = fmaxf(m, acc[1][nf][r]);
      m = fmaxf(m, __shfl_xor(m, 16));
      m = fmaxf(m, __shfl_xor(m, 32));
      float s = 0.f;
      #pragma unroll
      for (int mf=0;mf<2;++mf)
        #pragma unroll
        for (int r=0;r<4;++r) s += exp2f(acc[mf][nf][r]-m);
      s += __shfl_xor(s, 16);
      s += __shfl_xor(s, 32);
      cm[nf] = m; cs[nf] = s;
    }
    if (l < 16){
      #pragma unroll
      for (int nf=0; nf<8; ++nf){
        cmaxw[w*128 + nf*16 + l] = cm[nf];
        csumw[w*128 + nf*16 + l] = cs[nf];
      }
    }
    barrier_ndv();
    if (tid < 128){
      float m = cmaxw[tid];
      #pragma unroll
      for (int ww=1; ww<4; ++ww) m = fmaxf(m, cmaxw[ww*128 + tid]);
      float s = 0.f;
      #pragma unroll
      for (int ww=0; ww<4; ++ww)
        s += csumw[ww*128 + tid] * exp2f(cmaxw[ww*128 + tid]-m);
      size_t o = ((size_t)bh*16 + blockIdx.x)*2048 + jt + tid;
      pmax[o] = m; psum[o] = s;
    }
  }
  if ((l&15)==0){
    #pragma unroll
    for (int mf=0;mf<2;++mf)
      #pragma unroll
      for (int r=0;r<4;++r){
        int i = i0 + w*32 + mf*16 + (l>>4)*4 + r;
        size_t o = ((size_t)bh*4 + blockIdx.y)*2048 + i;
        rpm[o] = rmv[mf][r];
        rps[o] = rlv[mf][r];
      }
  }
}

// merge partials: y=0 row (4-way) -> rm0/rs0 ; y=1 col (16-way) -> rm1/rs1
__global__ __launch_bounds__(256) void reduce_k(
    const float* __restrict__ rpm, const float* __restrict__ rps,
    const float* __restrict__ pmax, const float* __restrict__ psum,
    float* __restrict__ rm0, float* __restrict__ rs0,
    float* __restrict__ rm1, float* __restrict__ rs1)
{
  int idx = blockIdx.x*256 + threadIdx.x;   // 32768
  int bh = idx >> 11, i = idx & 2047;
  if (blockIdx.y == 0){
    float pm[4], ps[4];
    #pragma unroll
    for (int c=0;c<4;++c){
      size_t o = ((size_t)bh*4 + c)*2048 + i;
      pm[c] = rpm[o]; ps[c] = rps[o];
    }
    float m = fmaxf(fmaxf(pm[0],pm[1]), fmaxf(pm[2],pm[3]));
    float s = 0.f;
    #pragma unroll
    for (int c=0;c<4;++c) s += ps[c] * exp2f(pm[c]-m);
    rm0[bh*2048 + i] = m;
    rs0[bh*2048 + i] = s;
  } else {
    float pm[16], ps[16];
    #pragma unroll
    for (int it=0; it<16; ++it){
      size_t o = ((size_t)bh*16 + it)*2048 + i;
      pm[it] = pmax[o]; ps[it] = psum[o];
    }
    float m = pm[0];
    #pragma unroll
    for (int it=1; it<16; ++it) m = fmaxf(m, pm[it]);
    float s = 0.f;
    #pragma unroll
    for (int it=0; it<16; ++it) s += ps[it] * exp2f(pm[it]-m);
    rm1[bh*2048 + i] = m;
    rs1[bh*2048 + i] = s;
  }
}

// ---------------- fused: recompute sim tile, write attn rows (nt), P*V -------
__global__ __launch_bounds__(256) void attn_k(
    const u16* __restrict__ qk0, const u16* __restrict__ qk1,
    const u16* __restrict__ vT0, const u16* __restrict__ vT1,
    const float* __restrict__ rm0, const float* __restrict__ rs0,
    const float* __restrict__ rm1, const float* __restrict__ rs1,
    u16* __restrict__ mo0, u16* __restrict__ mo1,
    float* __restrict__ dout)
{
  __shared__ u16 Ks[128*72];
  __shared__ u16 Vs[64*136];
  __shared__ u16 Ps[128*136];
  const int z = blockIdx.z;
  const u16* Q  = z ? qk1 : qk0;
  const u16* Kp = z ? qk0 : qk1;
  const u16* Vp = z ? vT0 : vT1;
  const float* rm = z ? rm1 : rm0;
  const float* rs = z ? rs1 : rs0;
  u16* mo = z ? mo1 : mo0;
  const int bh = blockIdx.y, i0 = blockIdx.x*128;
  float* aout = dout + (size_t)(z ? 71303168u : 4194304u) + (size_t)bh*4194304u;
  const int tid = threadIdx.x, w = tid>>6, l = tid&63;
  const u16* Qb = Q + (size_t)bh*2048*64;
  const u16* Kb = Kp + (size_t)bh*2048*64;
  const u16* Vb = Vp + (size_t)bh*64*2048;
  bf16x8 qf[2][2];
  #pragma unroll
  for (int mf=0; mf<2; ++mf)
    #pragma unroll
    for (int kf=0; kf<2; ++kf)
      qf[mf][kf] = *(const bf16x8*)&Qb[(size_t)(i0 + w*32 + mf*16 + (l&15))*64 + kf*32 + (l>>4)*8];
  float rmr[2][4], rir[2][4];
  #pragma unroll
  for (int mf=0;mf<2;++mf)
    #pragma unroll
    for (int r=0;r<4;++r){
      int i = i0 + w*32 + mf*16 + (l>>4)*4 + r;
      rmr[mf][r] = rm[bh*2048 + i];
      rir[mf][r] = 1.f / rs[bh*2048 + i];
    }
  const f32x4 z4 = {0.f,0.f,0.f,0.f};
  f32x4 macc[2][4];
  #pragma unroll
  for (int mf=0;mf<2;++mf)
    #pragma unroll
    for (int nf=0;nf<4;++nf) macc[mf][nf] = z4;
  const int krow = tid>>3, kc = (tid&7)*8;
  const int vd = tid>>4, vc = (tid&15)*8;
  uint4 kreg[4], vreg[4];
  #pragma unroll
  for (int r=0;r<4;++r){
    kreg[r] = *(const uint4*)&Kb[(size_t)(r*32+krow)*64 + kc];
    vreg[r] = *(const uint4*)&Vb[(size_t)(r*16+vd)*2048 + vc];
  }
  for (int jt=0; jt<2048; jt+=128){
    barrier_ndv();                       // prev PV done: Ks/Vs/Ps free
    #pragma unroll
    for (int r=0;r<4;++r) *(uint4*)&Ks[(r*32+krow)*72 + kc] = kreg[r];
    #pragma unroll
    for (int r=0;r<4;++r) *(uint4*)&Vs[(r*16+vd)*136 + vc] = vreg[r];
    if (jt+128 < 2048){
      #pragma unroll
      for (int r=0;r<4;++r){
        kreg[r] = *(const uint4*)&Kb[(size_t)(jt+128+r*32+krow)*64 + kc];
        vreg[r] = *(const uint4*)&Vb[(size_t)(r*16+vd)*2048 + jt+128 + vc];
      }
    }
    barrier_ndv();                       // Ks/Vs ready
    f32x4 acc[2][8];
    #pragma unroll
    for (int mf=0;mf<2;++mf)
      #pragma unroll
      for (int nf=0;nf<8;++nf) acc[mf][nf] = z4;
    #pragma unroll
    for (int nf=0; nf<8; ++nf){
      bf16x8 b0 = *(const bf16x8*)&Ks[(nf*16+(l&15))*72 + (l>>4)*8];
      bf16x8 b1 = *(const bf16x8*)&Ks[(nf*16+(l&15))*72 + 32 + (l>>4)*8];
      acc[0][nf] = mfma16(qf[0][0], b0, acc[0][nf]);
      acc[0][nf] = mfma16(qf[0][1], b1, acc[0][nf]);
      acc[1][nf] = mfma16(qf[1][0], b0, acc[1][nf]);
      acc[1][nf] = mfma16(qf[1][1], b1, acc[1][nf]);
    }
    #pragma unroll
    for (int mf=0;mf<2;++mf)
      #pragma unroll
      for (int nf=0;nf<8;++nf){
        int coll = nf*16 + (l&15);
        #pragma unroll
        for (int r=0;r<4;++r){
          int rowl = w*32 + mf*16 + (l>>4)*4 + r;
          float p = exp2f(acc[mf][nf][r]-rmr[mf][r]) * rir[mf][r];
          __builtin_nontemporal_store(p, &aout[(size_t)(i0+rowl)*2048 + jt + coll]);
          Ps[rowl*136 + coll] = f2bf(p);
        }
      }
    barrier_ndv();                       // Ps ready
    #pragma unroll
    for (int kf=0; kf<4; ++kf){
      bf16x8 pa0 = *(const bf16x8*)&Ps[(w*32 + (l&15))*136 + kf*32 + (l>>4)*8];
      bf16x8 pa1 = *(const bf16x8*)&Ps[(w*32 + 16 + (l&15))*136 + kf*32 + (l>>4)*8];
      #pragma unroll
      for (int nf=0; nf<4; ++nf){
        bf16x8 vb = *(const bf16x8*)&Vs[(nf*16+(l&15))*136 + kf*32 + (l>>4)*8];
        macc[0][nf] = mfma16(pa0, vb, macc[0][nf]);
        macc[1][nf] = mfma16(pa1, vb, macc[1][nf]);
      }
    }
  }
  int bb = bh>>2, hh = bh&3;
  #pragma unroll
  for (int mf=0;mf<2;++mf)
    #pragma unroll
    for (int nf=0;nf<4;++nf)
      #pragma unroll
      for (int r=0;r<4;++r){
        int n = i0 + w*32 + mf*16 + (l>>4)*4 + r;
        int d = nf*16 + (l&15);
        mo[(size_t)(bb*2048 + n)*256 + hh*64 + d] = f2bf(macc[mf][nf][r]);
      }
}

// ---------------- LayerNorm + exact GELU, in place on h[8192][512] ----------
__global__ __launch_bounds__(256) void ln_gelu_k(
    u16* __restrict__ h0, u16* __restrict__ h1,
    const float* __restrict__ g, const float* __restrict__ be)
{
  u16* h = blockIdx.y ? h1 : h0;
  int row = blockIdx.x*4 + (threadIdx.x>>6);
  int l = threadIdx.x & 63;
  u16* hr = h + (size_t)row*512;
  uint4 raw = *(const uint4*)&hr[l*8];
  u32 ua[4] = {raw.x, raw.y, raw.z, raw.w};
  float f[8];
  #pragma unroll
  for (int k=0;k<4;++k){
    f[2*k]   = bf2f((u16)(ua[k] & 0xFFFFu));
    f[2*k+1] = bf2f((u16)(ua[k] >> 16));
  }
  float s = 0.f, s2 = 0.f;
  #pragma unroll
  for (int k=0;k<8;++k){ s += f[k]; s2 += f[k]*f[k]; }
  #pragma unroll
  for (int o=1;o<64;o<<=1){ s += __shfl_xor(s,o); s2 += __shfl_xor(s2,o); }
  float mean = s * (1.f/512.f);
  float var  = s2 * (1.f/512.f) - mean*mean;
  float rstd = rsqrtf(var + 1e-5f);
  u32 ob[4];
  #pragma unroll
  for (int k=0;k<8;++k){
    int e = l*8 + k;
    float t = (f[k]-mean)*rstd*g[e] + be[e];
    float gl = 0.5f*t*(1.f + erff(t*0.70710678118654752f));
    u16 b = f2bf(gl);
    if (k&1) ob[k>>1] |= (u32)b << 16; else ob[k>>1] = (u32)b;
  }
  uint4 o4 = {ob[0],ob[1],ob[2],ob[3]};
  *(uint4*)&hr[l*8] = o4;
}

// ---------------- launch ----------------
extern "C" void kernel_launch(void* const* d_in, const int* in_sizes, int n_in,
                              void* d_out, int out_size, void* d_ws, size_t ws_size,
                              hipStream_t stream)
{
  const float* x0  = (const float*)d_in[0];
  const float* x1  = (const float*)d_in[1];
  const float* Wqk = (const float*)d_in[2];
  const float* bqk = (const float*)d_in[3];
  const float* Wv  = (const float*)d_in[4];
  const float* bv  = (const float*)d_in[5];
  const float* Wo  = (const float*)d_in[6];
  const float* bo  = (const float*)d_in[7];
  const float* W1  = (const float*)d_in[8];
  const float* b1  = (const float*)d_in[9];
  const float* gln = (const float*)d_in[10];
  const float* bln = (const float*)d_in[11];
  const float* W2  = (const float*)d_in[12];
  const float* b2  = (const float*)d_in[13];
  (void)in_sizes; (void)n_in; (void)out_size; (void)ws_size;
  float* out = (float*)d_out;
  char* ws = (char*)d_ws;
  size_t off = 0;
  auto alloc = [&](size_t bytes)->void*{
    void* p = ws + off; off += (bytes + 255) & ~(size_t)255; return p; };
  u16* xc0 = (u16*)alloc((size_t)8192*512*2);   // [m][512]: 0..255 x, 256..511 mo
  u16* xc1 = (u16*)alloc((size_t)8192*512*2);
  u16* Wqkv= (u16*)alloc((size_t)512*256*2);
  u16* WoB = (u16*)alloc((size_t)256*256*2);
  u16* W1B = (u16*)alloc((size_t)512*512*2);
  u16* W2B = (u16*)alloc((size_t)256*512*2);
  u16* qk0 = (u16*)alloc((size_t)16*2048*64*2); // [bh][n][d], exp2-domain scaled
  u16* qk1 = (u16*)alloc((size_t)16*2048*64*2);
  u16* v0  = (u16*)alloc((size_t)16*2048*64*2);
  u16* v1  = (u16*)alloc((size_t)16*2048*64*2);
  u16* vT0 = (u16*)alloc((size_t)16*2048*64*2); // [bh][d][n]
  u16* vT1 = (u16*)alloc((size_t)16*2048*64*2);
  u16* m0  = (u16*)alloc((size_t)8192*256*2);
  u16* m1  = (u16*)alloc((size_t)8192*256*2);
  u16* h0  = (u16*)alloc((size_t)8192*512*2);
  u16* h1  = (u16*)alloc((size_t)8192*512*2);
  float* rm0 = (float*)alloc((size_t)16*2048*4);
  float* rs0 = (float*)alloc((size_t)16*2048*4);
  float* rm1 = (float*)alloc((size_t)16*2048*4);
  float* rs1 = (float*)alloc((size_t)16*2048*4);
  float* pmax = (float*)alloc((size_t)16*16*2048*4);
  float* psum = (float*)alloc((size_t)16*16*2048*4);
  float* rpm  = (float*)alloc((size_t)16*4*2048*4);
  float* rps  = (float*)alloc((size_t)16*4*2048*4);

  cast_x_k<<<dim3(512,2), 256, 0, stream>>>(x0, x1, xc0, xc1);
  cast_w_k<<<dim3(256), 256, 0, stream>>>(Wqk, Wv, Wo, W1, W2, Wqkv, WoB, W1B, W2B);
  gemm_k<0,256,512><<<dim3(64,4,2), 256, 0, stream>>>(
      xc0, xc1, Wqkv, bqk, bv, qk0, qk1, v0, v1, nullptr, nullptr, nullptr);
  transp_k<<<dim3(32,16,2), 256, 0, stream>>>(v0, v1, vT0, vT1);
  stats2_k<<<dim3(16,4,16), 256, 0, stream>>>(qk0, qk1, rpm, rps, pmax, psum);
  reduce_k<<<dim3(128,2), 256, 0, stream>>>(rpm, rps, pmax, psum, rm0, rs0, rm1, rs1);
  attn_k<<<dim3(16,16,2), 256, 0, stream>>>(
      qk0, qk1, vT0, vT1, rm0, rs0, rm1, rs1, m0, m1, out);
  gemm_k<1,256,256><<<dim3(64,2,2), 256, 0, stream>>>(
      m0, m1, WoB, bo, nullptr, xc0, xc1, nullptr, nullptr, nullptr, nullptr, nullptr);
  gemm_k<2,512,512><<<dim3(64,4,2), 256, 0, stream>>>(
      xc0, xc1, W1B, b1, nullptr, h0, h1, nullptr, nullptr, nullptr, nullptr, nullptr);
  ln_gelu_k<<<dim3(2048,2), 256, 0, stream>>>(h0, h1, gln, bln);
  gemm_k<3,512,512><<<dim3(64,2,2), 256, 0, stream>>>(
      h0, h1, W2B, b2, nullptr, nullptr, nullptr, nullptr, nullptr, x0, x1, out);
}